// Round 13
// baseline (1931.000 us; speedup 1.0000x reference)
//
#include <hip/hip_runtime.h>

#define TW    10000
#define EMBD  100
#define SEQ   80
#define U     512
#define BATCH 2048
#define STATE_ELEMS (128 * 16 * 512)   // 1M elems = 2MB per parity buffer

typedef short short8 __attribute__((ext_vector_type(8)));
typedef float f32x4 __attribute__((ext_vector_type(4)));

static __device__ __forceinline__ unsigned short f2bf(float f){
  unsigned int u = __float_as_uint(f);
  u += 0x7fffu + ((u >> 16) & 1u);   // RNE
  return (unsigned short)(u >> 16);
}
static __device__ __forceinline__ float bf2f(unsigned short h){
  return __uint_as_float(((unsigned int)h) << 16);
}
static __device__ __forceinline__ float fast_tanh(float x){
  float e = __expf(2.0f * x);
  return 1.0f - 2.0f / (e + 1.0f);
}

// ---------------- proj[w][n] = b0[n] + sum_e emb[w][e] * Wx0[e][n] ----------------
__global__ void proj_kernel(const float* __restrict__ emb, const float* __restrict__ Wx0,
                            const float* __restrict__ b0, float* __restrict__ proj){
  __shared__ float es[16][EMBD];
  const int w0 = blockIdx.x * 16;
  for (int i = threadIdx.x; i < 16 * EMBD; i += 256)
    es[i / EMBD][i % EMBD] = emb[(size_t)w0 * EMBD + i];
  __syncthreads();
  const int n = threadIdx.x;
  float accA[16], accB[16];
#pragma unroll
  for (int wi = 0; wi < 16; ++wi){ accA[wi] = 0.0f; accB[wi] = 0.0f; }
  for (int e = 0; e < EMBD; ++e){
    const float wv0 = Wx0[(size_t)e * U + n];
    const float wv1 = Wx0[(size_t)e * U + n + 256];
#pragma unroll
    for (int wi = 0; wi < 16; ++wi){
      accA[wi] += es[wi][e] * wv0;
      accB[wi] += es[wi][e] * wv1;
    }
  }
  const float bb0 = b0[n], bb1 = b0[n + 256];
  for (int wi = 0; wi < 16; ++wi){
    proj[(size_t)(w0 + wi) * U + n]       = accA[wi] + bb0;
    proj[(size_t)(w0 + wi) * U + n + 256] = accB[wi] + bb1;
  }
}

// ---- pack [512][512] f32 -> per-colslice B-fragment order (bf16) ----
// dst[(((cs*4 + ct)*NCH + chL)*64 + lane)*8 + j], lane = khi*16 + (n&15)
__global__ void pack_w(const float* __restrict__ src, unsigned short* __restrict__ dst,
                       int chOff, int NCH){
  const int idx = blockIdx.x * 256 + threadIdx.x;
  if (idx >= U * U) return;
  const int k = idx / U, n = idx % U;
  const int cs = n >> 6, ct = (n >> 4) & 3, cl = n & 15;
  const int chL = (k >> 5) + chOff, khi = (k >> 3) & 3, j = k & 7;
  const int lane = khi * 16 + cl;
  const size_t di = ((((size_t)cs * 4 + ct) * NCH + chL) * 64 + lane) * 8 + j;
  dst[di] = f2bf(src[(size_t)k * U + n]);
}

static __device__ __forceinline__ void waitflag(int* p, int need){
  while (__hip_atomic_load(p, __ATOMIC_ACQUIRE, __HIP_MEMORY_SCOPE_AGENT) < need)
    __builtin_amdgcn_s_sleep(1);
}

// ---------------- 3-stage weight-stationary pipeline ----------------
// 192 blocks: bid&7 = row-slice r (256 rows), (bid>>3)>>3 = stage, (bid>>3)&7 = col-slice.
// Weights LDS-resident. States in global, fragment-packed, parity double-buffered.
// Flags f[stage][t][r] count producer col-blocks (==8 -> ready).
__global__ __launch_bounds__(1024, 4)
void rnn_pipeline(const int* __restrict__ tokens,
                  const float* __restrict__ proj,
                  const unsigned short* __restrict__ W0p,
                  const unsigned short* __restrict__ W1p,
                  const unsigned short* __restrict__ W2p,
                  const float* __restrict__ b1,
                  const float* __restrict__ b2,
                  const float* __restrict__ Wout,
                  const float* __restrict__ bout,
                  unsigned short* __restrict__ s0,
                  unsigned short* __restrict__ s1,
                  unsigned short* __restrict__ s2,
                  int* __restrict__ flags,
                  float* __restrict__ out)
{
  extern __shared__ unsigned char sm[];
  unsigned short* wlds = (unsigned short*)sm;             // <=128KB weights
  unsigned short* exch = (unsigned short*)(sm + 131072);  // 32KB epilogue exchange

  const int bid   = blockIdx.x;
  const int r     = bid & 7;
  const int q     = bid >> 3;
  const int stage = q >> 3;
  const int cs    = q & 7;

  const int tid  = threadIdx.x;
  const int lane = tid & 63;
  const int wid  = tid >> 6;
  const int l15  = lane & 15;
  const int khi  = lane >> 4;

  const int NCH = (stage == 0) ? 16 : 32;

  // ---- stage weights -> LDS (once) ----
  {
    const unsigned short* wsrc =
      (stage == 0 ? W0p : (stage == 1 ? W1p : W2p)) + (size_t)cs * 4 * NCH * 512;
    const int n8 = 4 * NCH * 512 / 8;
    for (int i = tid; i < n8; i += 1024)
      *reinterpret_cast<short8*>(&wlds[(size_t)i * 8]) =
        *reinterpret_cast<const short8*>(&wsrc[(size_t)i * 8]);
  }

  // wave tile: 2 row-tiles x 2 col-tiles
  const int rt0 = (wid >> 1) * 2, rt1 = rt0 + 1;
  const int ct0 = (wid & 1) * 2,  ct1 = ct0 + 1;
  const int rtG0 = r * 16 + rt0,  rtG1 = r * 16 + rt1;

  const int colL0 = ct0 * 16 + l15, colL1 = ct1 * 16 + l15;
  const int colG0 = cs * 64 + colL0, colG1 = cs * 64 + colL1;

  float bv0 = 0.0f, bv1 = 0.0f;
  if (stage == 1){ bv0 = b1[colG0]; bv1 = b1[colG1]; }
  if (stage == 2){ bv0 = b2[colG0]; bv1 = b2[colG1]; }

  unsigned short* outBase = (stage == 0) ? s0 : (stage == 1 ? s1 : s2);

  __syncthreads();

  for (int t = 0; t < SEQ; ++t){
    const int pw = t & 1, pr = pw ^ 1;

    // ---- input-ready + backpressure waits ----
    if (tid == 0){
      if (stage == 0){
        if (t >= 1) waitflag(&flags[(0 * SEQ + t - 1) * 8 + r], 8);
        if (t >= 2) waitflag(&flags[(1 * SEQ + t - 2) * 8 + r], 8);
      } else if (stage == 1){
        waitflag(&flags[(0 * SEQ + t) * 8 + r], 8);
        if (t >= 1) waitflag(&flags[(1 * SEQ + t - 1) * 8 + r], 8);
        if (t >= 2) waitflag(&flags[(2 * SEQ + t - 2) * 8 + r], 8);
      } else {
        waitflag(&flags[(1 * SEQ + t) * 8 + r], 8);
        if (t >= 1) waitflag(&flags[(2 * SEQ + t - 1) * 8 + r], 8);
      }
    }
    __syncthreads();

    const unsigned short* bufLow =
      (stage == 0) ? s0 + (size_t)pr * STATE_ELEMS :
      (stage == 1) ? s0 + (size_t)pw * STATE_ELEMS :
                     s1 + (size_t)pw * STATE_ELEMS;
    const unsigned short* bufHigh =
      (stage == 0) ? bufLow :
      (stage == 1) ? s1 + (size_t)pr * STATE_ELEMS :
                     s2 + (size_t)pr * STATE_ELEMS;

    f32x4 a00 = 0.0f, a01 = 0.0f, a10 = 0.0f, a11 = 0.0f;

#pragma unroll 4
    for (int ch = 0; ch < NCH; ++ch){
      const unsigned short* ab = (ch < 16) ? bufLow : bufHigh;
      const int chL = ch & 15;
      short8 A0 = *reinterpret_cast<const short8*>(ab + ((size_t)(rtG0 * 16 + chL) * 64 + lane) * 8);
      short8 A1 = *reinterpret_cast<const short8*>(ab + ((size_t)(rtG1 * 16 + chL) * 64 + lane) * 8);
      short8 B0 = *reinterpret_cast<const short8*>(wlds + ((size_t)(ct0 * NCH + ch) * 64 + lane) * 8);
      short8 B1 = *reinterpret_cast<const short8*>(wlds + ((size_t)(ct1 * NCH + ch) * 64 + lane) * 8);
      a00 = __builtin_amdgcn_mfma_f32_16x16x32_bf16(A0, B0, a00, 0, 0, 0);
      a01 = __builtin_amdgcn_mfma_f32_16x16x32_bf16(A0, B1, a01, 0, 0, 0);
      a10 = __builtin_amdgcn_mfma_f32_16x16x32_bf16(A1, B0, a10, 0, 0, 0);
      a11 = __builtin_amdgcn_mfma_f32_16x16x32_bf16(A1, B1, a11, 0, 0, 0);
    }

    // ---- epilogue: tanh(+proj/bias) -> exch (row-swizzled) ----
    const int g0 = colL0 >> 3, g1 = colL1 >> 3, j0 = colL0 & 7, j1 = colL1 & 7;
#pragma unroll
    for (int h = 0; h < 2; ++h){
      const int rtL = h ? rt1 : rt0;
      const f32x4 accA = h ? a10 : a00;
      const f32x4 accB = h ? a11 : a01;
#pragma unroll
      for (int g = 0; g < 4; ++g){
        const int rowL = rtL * 16 + khi * 4 + g;
        float z0, z1;
        if (stage == 0){
          const int tok = tokens[(size_t)(r * 256 + rowL) * SEQ + t];
          z0 = accA[g] + proj[(size_t)tok * U + colG0];
          z1 = accB[g] + proj[(size_t)tok * U + colG1];
        } else {
          z0 = accA[g] + bv0;
          z1 = accB[g] + bv1;
        }
        const int sw = rowL & 7;
        exch[rowL * 64 + ((g0 ^ sw) << 3) + j0] = f2bf(fast_tanh(z0));
        exch[rowL * 64 + ((g1 ^ sw) << 3) + j1] = f2bf(fast_tanh(z1));
      }
    }
    __syncthreads();

    // ---- packed fragment write to global state (2 x 1KB per wave) ----
    unsigned short* ob = outBase + (size_t)pw * STATE_ELEMS;
#pragma unroll
    for (int u = 0; u < 2; ++u){
      const int un  = wid * 2 + u;
      const int rtL = un >> 1;
      const int che = un & 1;
      const int rowE = rtL * 16 + l15;
      const int gg = che * 4 + khi;
      short8 v = *reinterpret_cast<const short8*>(&exch[rowE * 64 + ((gg ^ (rowE & 7)) << 3)]);
      *reinterpret_cast<short8*>(ob + ((size_t)((r * 16 + rtL) * 16 + (cs * 2 + che)) * 64 + lane) * 8) = v;
    }
    __syncthreads();   // drains all stores (vmcnt) before flagging

    if (tid == 0)
      __hip_atomic_fetch_add(&flags[(stage * SEQ + t) * 8 + r], 1,
                             __ATOMIC_RELEASE, __HIP_MEMORY_SCOPE_AGENT);
  }

  // ---- final output: sigmoid(s2(79) @ Wout + bout) by stage2/cs==0 blocks ----
  if (stage == 2 && cs == 0){
    if (tid == 0) waitflag(&flags[(2 * SEQ + SEQ - 1) * 8 + r], 8);
    __syncthreads();
    const unsigned short* sf = s2 + (size_t)((SEQ - 1) & 1) * STATE_ELEMS;
    const int rtG = r * 16 + wid;
    float v = 0.0f;
#pragma unroll
    for (int ch = 0; ch < 16; ++ch){
      short8 a = *reinterpret_cast<const short8*>(sf + ((size_t)(rtG * 16 + ch) * 64 + lane) * 8);
      const float* wp = Wout + ch * 32 + khi * 8;
#pragma unroll
      for (int j = 0; j < 8; ++j) v += bf2f((unsigned short)a[j]) * wp[j];
    }
    v += __shfl_xor(v, 16, 64);
    v += __shfl_xor(v, 32, 64);
    if (lane < 16)
      out[r * 256 + wid * 16 + lane] = 1.0f / (1.0f + __expf(-(v + bout[0])));
  }
}

extern "C" void kernel_launch(void* const* d_in, const int* in_sizes, int n_in,
                              void* d_out, int out_size, void* d_ws, size_t ws_size,
                              hipStream_t stream){
  (void)in_sizes; (void)n_in; (void)out_size; (void)ws_size;
  const int*   tokens = (const int*)  d_in[0];
  const float* emb  = (const float*)d_in[1];
  const float* Wx0  = (const float*)d_in[2];
  const float* Wh0  = (const float*)d_in[3];
  const float* b0   = (const float*)d_in[4];
  const float* Wx1  = (const float*)d_in[5];
  const float* Wh1  = (const float*)d_in[6];
  const float* b1   = (const float*)d_in[7];
  const float* Wx2  = (const float*)d_in[8];
  const float* Wh2  = (const float*)d_in[9];
  const float* b2   = (const float*)d_in[10];
  const float* Wout = (const float*)d_in[11];
  const float* bout = (const float*)d_in[12];

  char* ws = (char*)d_ws;
  float* proj = (float*)ws;                                       // 20,480,000 B
  unsigned short* W0p = (unsigned short*)(ws + 20480000);         // 512 KB
  unsigned short* W1p = (unsigned short*)(ws + 21004288);         // 1 MB
  unsigned short* W2p = (unsigned short*)(ws + 22052864);         // 1 MB
  unsigned short* s0  = (unsigned short*)(ws + 23101440);         // 2 x 2 MB
  unsigned short* s1  = (unsigned short*)(ws + 27295744);         // 2 x 2 MB
  unsigned short* s2  = (unsigned short*)(ws + 31490048);         // 2 x 2 MB
  int* flags          = (int*)(ws + 35684352);                    // 7680 B

  // deterministic reset each launch (graph-capture-safe)
  hipMemsetAsync(s0 + STATE_ELEMS, 0, (size_t)STATE_ELEMS * 2, stream);
  hipMemsetAsync(s1 + STATE_ELEMS, 0, (size_t)STATE_ELEMS * 2, stream);
  hipMemsetAsync(s2 + STATE_ELEMS, 0, (size_t)STATE_ELEMS * 2, stream);
  hipMemsetAsync(flags, 0, 3 * SEQ * 8 * sizeof(int), stream);

  proj_kernel<<<TW / 16, 256, 0, stream>>>(emb, Wx0, b0, proj);
  const int pblk = (U * U + 255) / 256;
  pack_w<<<pblk, 256, 0, stream>>>(Wh0, W0p, 0, 16);
  pack_w<<<pblk, 256, 0, stream>>>(Wx1, W1p, 0, 32);
  pack_w<<<pblk, 256, 0, stream>>>(Wh1, W1p, 16, 32);
  pack_w<<<pblk, 256, 0, stream>>>(Wx2, W2p, 0, 32);
  pack_w<<<pblk, 256, 0, stream>>>(Wh2, W2p, 16, 32);

  static const int kLds = 163840;   // 128 KB weights + 32 KB exch
  (void)hipFuncSetAttribute((const void*)rnn_pipeline,
                            hipFuncAttributeMaxDynamicSharedMemorySize, kLds);
  rnn_pipeline<<<192, 1024, kLds, stream>>>(tokens, proj, W0p, W1p, W2p,
                                            b1, b2, Wout, bout,
                                            s0, s1, s2, flags, (float*)d_out);
}

// Round 14
// 1713.743 us; speedup vs baseline: 1.1268x; 1.1268x over previous
//
#include <hip/hip_runtime.h>

#define TW    10000
#define EMBD  100
#define SEQ   80
#define U     512
#define BATCH 2048
#define STATE_ELEMS (128 * 16 * 512)   // 1M elems = 2MB per parity buffer

typedef short short8 __attribute__((ext_vector_type(8)));
typedef float f32x4 __attribute__((ext_vector_type(4)));

static __device__ __forceinline__ unsigned short f2bf(float f){
  unsigned int u = __float_as_uint(f);
  u += 0x7fffu + ((u >> 16) & 1u);   // RNE
  return (unsigned short)(u >> 16);
}
static __device__ __forceinline__ float bf2f(unsigned short h){
  return __uint_as_float(((unsigned int)h) << 16);
}
static __device__ __forceinline__ float fast_tanh(float x){
  float e = __expf(2.0f * x);
  return 1.0f - 2.0f / (e + 1.0f);
}

// ---------------- proj[w][n] = b0[n] + sum_e emb[w][e] * Wx0[e][n] ----------------
__global__ void proj_kernel(const float* __restrict__ emb, const float* __restrict__ Wx0,
                            const float* __restrict__ b0, float* __restrict__ proj){
  __shared__ float es[16][EMBD];
  const int w0 = blockIdx.x * 16;
  for (int i = threadIdx.x; i < 16 * EMBD; i += 256)
    es[i / EMBD][i % EMBD] = emb[(size_t)w0 * EMBD + i];
  __syncthreads();
  const int n = threadIdx.x;
  float accA[16], accB[16];
#pragma unroll
  for (int wi = 0; wi < 16; ++wi){ accA[wi] = 0.0f; accB[wi] = 0.0f; }
  for (int e = 0; e < EMBD; ++e){
    const float wv0 = Wx0[(size_t)e * U + n];
    const float wv1 = Wx0[(size_t)e * U + n + 256];
#pragma unroll
    for (int wi = 0; wi < 16; ++wi){
      accA[wi] += es[wi][e] * wv0;
      accB[wi] += es[wi][e] * wv1;
    }
  }
  const float bb0 = b0[n], bb1 = b0[n + 256];
  for (int wi = 0; wi < 16; ++wi){
    proj[(size_t)(w0 + wi) * U + n]       = accA[wi] + bb0;
    proj[(size_t)(w0 + wi) * U + n + 256] = accB[wi] + bb1;
  }
}

// ---- pack [512][512] f32 -> per-colslice B-fragment order (bf16) ----
__global__ void pack_w(const float* __restrict__ src, unsigned short* __restrict__ dst,
                       int chOff, int NCH){
  const int idx = blockIdx.x * 256 + threadIdx.x;
  if (idx >= U * U) return;
  const int k = idx / U, n = idx % U;
  const int cs = n >> 6, ct = (n >> 4) & 3, cl = n & 15;
  const int chL = (k >> 5) + chOff, khi = (k >> 3) & 3, j = k & 7;
  const int lane = khi * 16 + cl;
  const size_t di = ((((size_t)cs * 4 + ct) * NCH + chL) * 64 + lane) * 8 + j;
  dst[di] = f2bf(src[(size_t)k * U + n]);
}

// Relaxed spin (no cache-op per poll; agent-scope relaxed atomics read the
// coherent point), then ONE acquire load for the needed L2 invalidate.
static __device__ __forceinline__ void waitflag(int* p, int need){
  while (__hip_atomic_load(p, __ATOMIC_RELAXED, __HIP_MEMORY_SCOPE_AGENT) < need)
    __builtin_amdgcn_s_sleep(2);
  (void)__hip_atomic_load(p, __ATOMIC_ACQUIRE, __HIP_MEMORY_SCOPE_AGENT);
}

// ---------------- 3-stage weight-stationary pipeline ----------------
__global__ __launch_bounds__(1024, 4)
void rnn_pipeline(const int* __restrict__ tokens,
                  const float* __restrict__ proj,
                  const unsigned short* __restrict__ W0p,
                  const unsigned short* __restrict__ W1p,
                  const unsigned short* __restrict__ W2p,
                  const float* __restrict__ b1,
                  const float* __restrict__ b2,
                  const float* __restrict__ Wout,
                  const float* __restrict__ bout,
                  unsigned short* __restrict__ s0,
                  unsigned short* __restrict__ s1,
                  unsigned short* __restrict__ s2,
                  int* __restrict__ flags,
                  float* __restrict__ out)
{
  extern __shared__ unsigned char sm[];
  unsigned short* wlds = (unsigned short*)sm;             // <=128KB weights
  unsigned short* exch = (unsigned short*)(sm + 131072);  // 32KB epilogue exchange

  const int bid   = blockIdx.x;
  const int r     = bid & 7;
  const int q     = bid >> 3;
  const int stage = q >> 3;
  const int cs    = q & 7;

  const int tid  = threadIdx.x;
  const int lane = tid & 63;
  const int wid  = tid >> 6;
  const int l15  = lane & 15;
  const int khi  = lane >> 4;

  const int NCH = (stage == 0) ? 16 : 32;

  // ---- stage weights -> LDS (once) ----
  {
    const unsigned short* wsrc =
      (stage == 0 ? W0p : (stage == 1 ? W1p : W2p)) + (size_t)cs * 4 * NCH * 512;
    const int n8 = 4 * NCH * 512 / 8;
    for (int i = tid; i < n8; i += 1024)
      *reinterpret_cast<short8*>(&wlds[(size_t)i * 8]) =
        *reinterpret_cast<const short8*>(&wsrc[(size_t)i * 8]);
  }

  // wave tile: 2 row-tiles x 2 col-tiles
  const int rt0 = (wid >> 1) * 2, rt1 = rt0 + 1;
  const int ct0 = (wid & 1) * 2,  ct1 = ct0 + 1;
  const int rtG0 = r * 16 + rt0,  rtG1 = r * 16 + rt1;

  const int colL0 = ct0 * 16 + l15, colL1 = ct1 * 16 + l15;
  const int colG0 = cs * 64 + colL0, colG1 = cs * 64 + colL1;

  float bv0 = 0.0f, bv1 = 0.0f;
  if (stage == 1){ bv0 = b1[colG0]; bv1 = b1[colG1]; }
  if (stage == 2){ bv0 = b2[colG0]; bv1 = b2[colG1]; }

  unsigned short* outBase = (stage == 0) ? s0 : (stage == 1 ? s1 : s2);

  __syncthreads();

  for (int t = 0; t < SEQ; ++t){
    const int pw = t & 1, pr = pw ^ 1;

    // ---- input-ready + backpressure waits ----
    if (tid == 0){
      if (stage == 0){
        if (t >= 1) waitflag(&flags[(0 * SEQ + t - 1) * 8 + r], 8);
        if (t >= 2) waitflag(&flags[(1 * SEQ + t - 2) * 8 + r], 8);
      } else if (stage == 1){
        waitflag(&flags[(0 * SEQ + t) * 8 + r], 8);
        if (t >= 1) waitflag(&flags[(1 * SEQ + t - 1) * 8 + r], 8);
        if (t >= 2) waitflag(&flags[(2 * SEQ + t - 2) * 8 + r], 8);
      } else {
        waitflag(&flags[(1 * SEQ + t) * 8 + r], 8);
        if (t >= 1) waitflag(&flags[(2 * SEQ + t - 1) * 8 + r], 8);
      }
    }
    __syncthreads();

    const unsigned short* bufLow =
      (stage == 0) ? s0 + (size_t)pr * STATE_ELEMS :
      (stage == 1) ? s0 + (size_t)pw * STATE_ELEMS :
                     s1 + (size_t)pw * STATE_ELEMS;
    const unsigned short* bufHigh =
      (stage == 0) ? bufLow :
      (stage == 1) ? s1 + (size_t)pr * STATE_ELEMS :
                     s2 + (size_t)pr * STATE_ELEMS;

    f32x4 a00 = 0.0f, a01 = 0.0f, a10 = 0.0f, a11 = 0.0f;

#pragma unroll 4
    for (int ch = 0; ch < NCH; ++ch){
      const unsigned short* ab = (ch < 16) ? bufLow : bufHigh;
      const int chL = ch & 15;
      short8 A0 = *reinterpret_cast<const short8*>(ab + ((size_t)(rtG0 * 16 + chL) * 64 + lane) * 8);
      short8 A1 = *reinterpret_cast<const short8*>(ab + ((size_t)(rtG1 * 16 + chL) * 64 + lane) * 8);
      short8 B0 = *reinterpret_cast<const short8*>(wlds + ((size_t)(ct0 * NCH + ch) * 64 + lane) * 8);
      short8 B1 = *reinterpret_cast<const short8*>(wlds + ((size_t)(ct1 * NCH + ch) * 64 + lane) * 8);
      a00 = __builtin_amdgcn_mfma_f32_16x16x32_bf16(A0, B0, a00, 0, 0, 0);
      a01 = __builtin_amdgcn_mfma_f32_16x16x32_bf16(A0, B1, a01, 0, 0, 0);
      a10 = __builtin_amdgcn_mfma_f32_16x16x32_bf16(A1, B0, a10, 0, 0, 0);
      a11 = __builtin_amdgcn_mfma_f32_16x16x32_bf16(A1, B1, a11, 0, 0, 0);
    }

    // ---- epilogue: tanh(+proj/bias) -> exch (row-swizzled) ----
    const int g0 = colL0 >> 3, g1 = colL1 >> 3, j0 = colL0 & 7, j1 = colL1 & 7;
#pragma unroll
    for (int h = 0; h < 2; ++h){
      const int rtL = h ? rt1 : rt0;
      const f32x4 accA = h ? a10 : a00;
      const f32x4 accB = h ? a11 : a01;
#pragma unroll
      for (int g = 0; g < 4; ++g){
        const int rowL = rtL * 16 + khi * 4 + g;
        float z0, z1;
        if (stage == 0){
          const int tok = tokens[(size_t)(r * 256 + rowL) * SEQ + t];
          z0 = accA[g] + proj[(size_t)tok * U + colG0];
          z1 = accB[g] + proj[(size_t)tok * U + colG1];
        } else {
          z0 = accA[g] + bv0;
          z1 = accB[g] + bv1;
        }
        const int sw = rowL & 7;
        exch[rowL * 64 + ((g0 ^ sw) << 3) + j0] = f2bf(fast_tanh(z0));
        exch[rowL * 64 + ((g1 ^ sw) << 3) + j1] = f2bf(fast_tanh(z1));
      }
    }
    __syncthreads();

    // ---- packed fragment write to global state (2 x 1KB per wave) ----
    unsigned short* ob = outBase + (size_t)pw * STATE_ELEMS;
#pragma unroll
    for (int u = 0; u < 2; ++u){
      const int un  = wid * 2 + u;
      const int rtL = un >> 1;
      const int che = un & 1;
      const int rowE = rtL * 16 + l15;
      const int gg = che * 4 + khi;
      short8 v = *reinterpret_cast<const short8*>(&exch[rowE * 64 + ((gg ^ (rowE & 7)) << 3)]);
      *reinterpret_cast<short8*>(ob + ((size_t)((r * 16 + rtL) * 16 + (cs * 2 + che)) * 64 + lane) * 8) = v;
    }
    __syncthreads();   // drains all stores (vmcnt) before flagging

    if (tid == 0)
      __hip_atomic_fetch_add(&flags[(stage * SEQ + t) * 8 + r], 1,
                             __ATOMIC_RELEASE, __HIP_MEMORY_SCOPE_AGENT);
  }

  // ---- final output: sigmoid(s2(79) @ Wout + bout) by stage2/cs==0 blocks ----
  if (stage == 2 && cs == 0){
    if (tid == 0) waitflag(&flags[(2 * SEQ + SEQ - 1) * 8 + r], 8);
    __syncthreads();
    const unsigned short* sf = s2 + (size_t)((SEQ - 1) & 1) * STATE_ELEMS;
    const int rtG = r * 16 + wid;
    float v = 0.0f;
#pragma unroll
    for (int ch = 0; ch < 16; ++ch){
      short8 a = *reinterpret_cast<const short8*>(sf + ((size_t)(rtG * 16 + ch) * 64 + lane) * 8);
      const float* wp = Wout + ch * 32 + khi * 8;
#pragma unroll
      for (int j = 0; j < 8; ++j) v += bf2f((unsigned short)a[j]) * wp[j];
    }
    v += __shfl_xor(v, 16, 64);
    v += __shfl_xor(v, 32, 64);
    if (lane < 16)
      out[r * 256 + wid * 16 + lane] = 1.0f / (1.0f + __expf(-(v + bout[0])));
  }
}

extern "C" void kernel_launch(void* const* d_in, const int* in_sizes, int n_in,
                              void* d_out, int out_size, void* d_ws, size_t ws_size,
                              hipStream_t stream){
  (void)in_sizes; (void)n_in; (void)out_size; (void)ws_size;
  const int*   tokens = (const int*)  d_in[0];
  const float* emb  = (const float*)d_in[1];
  const float* Wx0  = (const float*)d_in[2];
  const float* Wh0  = (const float*)d_in[3];
  const float* b0   = (const float*)d_in[4];
  const float* Wx1  = (const float*)d_in[5];
  const float* Wh1  = (const float*)d_in[6];
  const float* b1   = (const float*)d_in[7];
  const float* Wx2  = (const float*)d_in[8];
  const float* Wh2  = (const float*)d_in[9];
  const float* b2   = (const float*)d_in[10];
  const float* Wout = (const float*)d_in[11];
  const float* bout = (const float*)d_in[12];

  char* ws = (char*)d_ws;
  float* proj = (float*)ws;                                       // 20,480,000 B
  unsigned short* W0p = (unsigned short*)(ws + 20480000);         // 512 KB
  unsigned short* W1p = (unsigned short*)(ws + 21004288);         // 1 MB
  unsigned short* W2p = (unsigned short*)(ws + 22052864);         // 1 MB
  unsigned short* s0  = (unsigned short*)(ws + 23101440);         // 2 x 2 MB
  unsigned short* s1  = (unsigned short*)(ws + 27295744);         // 2 x 2 MB
  unsigned short* s2  = (unsigned short*)(ws + 31490048);         // 2 x 2 MB
  int* flags          = (int*)(ws + 35684352);                    // 7680 B

  // deterministic reset each launch (graph-capture-safe)
  hipMemsetAsync(s0 + STATE_ELEMS, 0, (size_t)STATE_ELEMS * 2, stream);
  hipMemsetAsync(s1 + STATE_ELEMS, 0, (size_t)STATE_ELEMS * 2, stream);
  hipMemsetAsync(s2 + STATE_ELEMS, 0, (size_t)STATE_ELEMS * 2, stream);
  hipMemsetAsync(flags, 0, 3 * SEQ * 8 * sizeof(int), stream);

  proj_kernel<<<TW / 16, 256, 0, stream>>>(emb, Wx0, b0, proj);
  const int pblk = (U * U + 255) / 256;
  pack_w<<<pblk, 256, 0, stream>>>(Wh0, W0p, 0, 16);
  pack_w<<<pblk, 256, 0, stream>>>(Wx1, W1p, 0, 32);
  pack_w<<<pblk, 256, 0, stream>>>(Wh1, W1p, 16, 32);
  pack_w<<<pblk, 256, 0, stream>>>(Wx2, W2p, 0, 32);
  pack_w<<<pblk, 256, 0, stream>>>(Wh2, W2p, 16, 32);

  static const int kLds = 163840;   // 128 KB weights + 32 KB exch
  (void)hipFuncSetAttribute((const void*)rnn_pipeline,
                            hipFuncAttributeMaxDynamicSharedMemorySize, kLds);
  rnn_pipeline<<<192, 1024, kLds, stream>>>(tokens, proj, W0p, W1p, W2p,
                                            b1, b2, Wout, bout,
                                            s0, s1, s2, flags, (float*)d_out);
}

// Round 15
// 1656.514 us; speedup vs baseline: 1.1657x; 1.0345x over previous
//
#include <hip/hip_runtime.h>

#define TW    10000
#define EMBD  100
#define SEQ   80
#define U     512
#define BATCH 2048
#define RPB   16
#define NBLK  (BATCH / RPB)   // 128 blocks
#define NTHR  1024            // 16 waves/block

typedef short short8 __attribute__((ext_vector_type(8)));
typedef float f32x4 __attribute__((ext_vector_type(4)));

static __device__ __forceinline__ unsigned short f2bf(float f){
  unsigned int u = __float_as_uint(f);
  u += 0x7fffu + ((u >> 16) & 1u);   // RNE
  return (unsigned short)(u >> 16);
}
static __device__ __forceinline__ float bf2f(unsigned short h){
  return __uint_as_float(((unsigned int)h) << 16);
}
static __device__ __forceinline__ float fast_tanh(float x){
  float e = __expf(2.0f * x);        // inf-safe: saturates to +-1
  return 1.0f - 2.0f / (e + 1.0f);
}

// ---------------- proj[w][n] = b0[n] + sum_e emb[w][e] * Wx0[e][n] ----------------
__global__ void proj_kernel(const float* __restrict__ emb, const float* __restrict__ Wx0,
                            const float* __restrict__ b0, float* __restrict__ proj){
  __shared__ float es[16][EMBD];
  const int w0 = blockIdx.x * 16;
  for (int i = threadIdx.x; i < 16 * EMBD; i += 256)
    es[i / EMBD][i % EMBD] = emb[(size_t)w0 * EMBD + i];
  __syncthreads();
  const int n = threadIdx.x;   // cols n and n+256
  float accA[16], accB[16];
#pragma unroll
  for (int wi = 0; wi < 16; ++wi){ accA[wi] = 0.0f; accB[wi] = 0.0f; }
  for (int e = 0; e < EMBD; ++e){
    const float wv0 = Wx0[(size_t)e * U + n];
    const float wv1 = Wx0[(size_t)e * U + n + 256];
#pragma unroll
    for (int wi = 0; wi < 16; ++wi){
      accA[wi] += es[wi][e] * wv0;
      accB[wi] += es[wi][e] * wv1;
    }
  }
  const float bb0 = b0[n], bb1 = b0[n + 256];
  for (int wi = 0; wi < 16; ++wi){
    proj[(size_t)(w0 + wi) * U + n]       = accA[wi] + bb0;
    proj[(size_t)(w0 + wi) * U + n + 256] = accB[wi] + bb1;
  }
}

// ---- pack src[K][512] f32 into MFMA-fragment order (bf16) ----
// dest elem index for source (k+kOff, n):
//   wid=n>>5, t=(n>>4)&1, c=n&15, kk=k+kOff, ch=kk>>5, khi=(kk>>3)&3, j=kk&7
//   di = wid*NCH*1024 + ch*1024 + t*512 + (khi*16+c)*8 + j
// In-kernel B-load then is: base + wid*NCH*1024 + ch*1024 + t*512 + lane*8
// -> one contiguous 1KB per wave-load (lane*16B), ~8 cache lines vs 64.
__global__ void pack_frag(const float* __restrict__ src, unsigned short* __restrict__ dst,
                          int K, int kOff, int NCH){
  const int idx = blockIdx.x * 256 + threadIdx.x;
  if (idx >= K * 512) return;
  const int k = idx / 512, n = idx % 512;     // reads coalesced over n
  const int wid = n >> 5, t = (n >> 4) & 1, c = n & 15;
  const int kk = k + kOff;
  const int ch = kk >> 5, khi = (kk >> 3) & 3, j = kk & 7;
  const size_t di = (size_t)wid * NCH * 1024 + (size_t)ch * 1024
                  + (size_t)t * 512 + (size_t)(khi * 16 + c) * 8 + j;
  dst[di] = f2bf(src[(size_t)k * 512 + n]);
}

// One GEMM segment over NCH chunks of 32 k. B from packed fragment layout:
// per chunk, two contiguous 1KB loads (lane-ordered). A from swizzled state LDS.
template<int NCH>
static __device__ __forceinline__ void run_segment(
    const unsigned short* __restrict__ Wp,     // this wave's packed base
    unsigned lofs,                             // lane*8 elem offset
    const unsigned short* __restrict__ stA0, const unsigned short* __restrict__ stA1,
    int aBase, int aSwz, f32x4* acc)
{
#pragma unroll 8
  for (int ch = 0; ch < NCH; ++ch){
    const unsigned short* sA = (NCH == 16 || ch < 16) ? stA0 : stA1;
    short8 a  = *reinterpret_cast<const short8*>(&sA[(aBase + (ch & 15) * 32) ^ aSwz]);
    short8 b0 = *reinterpret_cast<const short8*>(Wp + (unsigned)(ch * 1024) + lofs);
    short8 b1 = *reinterpret_cast<const short8*>(Wp + (unsigned)(ch * 1024 + 512) + lofs);
    acc[0] = __builtin_amdgcn_mfma_f32_16x16x32_bf16(a, b0, acc[0], 0, 0, 0);
    acc[1] = __builtin_amdgcn_mfma_f32_16x16x32_bf16(a, b1, acc[1], 0, 0, 0);
  }
}

// ---------------- persistent per-block RNN: 16 rows through all 80 steps ----------------
// Double-buffered states: seg reads buffer [t&1], epilogue writes [t&1 ^ 1].
// Disjoint read/write buffers -> only 2 visibility barriers per step
// (o0 -> seg1, o1 -> seg2); the t->t+1 boundary is covered by the next
// step's own barriers (dependency distance >= 2 barriers for every pair).
__global__ __launch_bounds__(NTHR, 4)
void rnn_persist(const int* __restrict__ tokens,
                 const float* __restrict__ proj,
                 const unsigned short* __restrict__ P0,
                 const unsigned short* __restrict__ P1,
                 const unsigned short* __restrict__ P2,
                 const float* __restrict__ b1,
                 const float* __restrict__ b2,
                 const float* __restrict__ Wout,
                 const float* __restrict__ bout,
                 float* __restrict__ out)
{
  extern __shared__ unsigned short smem[];   // 6 x 8192 elems = 96 KiB
  // layer L, buffer b: smem + (L*2 + b) * 8192

  const int tid = threadIdx.x;
  for (int i = tid; i < 6 * 8192; i += NTHR) smem[i] = 0;
  __syncthreads();

  const int lane = tid & 63;
  const int wid  = tid >> 6;          // 16 waves, 32 output cols each
  const int l15  = lane & 15;
  const int khi  = lane >> 4;         // 0..3
  const int n0   = wid * 32;
  const int rowbase = blockIdx.x * RPB;

  // A-frag LDS elem address: row l15, k = ch*32 + khi*8 + j ; swizzle bits 3..5 by row
  const int aBase = l15 * U + khi * 8;
  const int aSwz  = (l15 & 7) << 3;

  // packed B bases for this wave + per-lane offset
  const unsigned short* w0p = P0 + (size_t)wid * 16 * 1024;
  const unsigned short* w1p = P1 + (size_t)wid * 32 * 1024;
  const unsigned short* w2p = P2 + (size_t)wid * 32 * 1024;
  const unsigned lofs = (unsigned)lane * 8;

  const int col0 = n0 + l15;
  const int col1 = n0 + 16 + l15;
  const float b1v0 = b1[col0], b1v1 = b1[col1];
  const float b2v0 = b2[col0], b2v1 = b2[col1];
  const int rr0 = khi * 4;

  f32x4 acc[2];

  for (int t = 0; t < SEQ; ++t){
    const int c = t & 1;
    unsigned short* s0r = smem + (0 + c)     * 8192;
    unsigned short* s0w = smem + (0 + (c^1)) * 8192;
    unsigned short* s1r = smem + (2 + c)     * 8192;
    unsigned short* s1w = smem + (2 + (c^1)) * 8192;
    unsigned short* s2r = smem + (4 + c)     * 8192;
    unsigned short* s2w = smem + (4 + (c^1)) * 8192;

    // hoisted token + proj gather (L2+L3 latency hides under seg0's stream)
    const int tk0 = tokens[(size_t)(rowbase + rr0 + 0) * SEQ + t];
    const int tk1 = tokens[(size_t)(rowbase + rr0 + 1) * SEQ + t];
    const int tk2 = tokens[(size_t)(rowbase + rr0 + 2) * SEQ + t];
    const int tk3 = tokens[(size_t)(rowbase + rr0 + 3) * SEQ + t];
    const float pj00 = proj[(size_t)tk0 * U + col0];
    const float pj01 = proj[(size_t)tk1 * U + col0];
    const float pj02 = proj[(size_t)tk2 * U + col0];
    const float pj03 = proj[(size_t)tk3 * U + col0];
    const float pj10 = proj[(size_t)tk0 * U + col1];
    const float pj11 = proj[(size_t)tk1 * U + col1];
    const float pj12 = proj[(size_t)tk2 * U + col1];
    const float pj13 = proj[(size_t)tk3 * U + col1];

    // ---------- layer 0: o0 = tanh(proj[tok] + s0 @ Wh0) ----------
    acc[0] = 0.0f; acc[1] = 0.0f;
    run_segment<16>(w0p, lofs, s0r, s0r, aBase, aSwz, acc);
    // epilogue writes s0w (disjoint from s0r readers) - no barrier needed before
    {
      s0w[((rr0 + 0) * U + col0) ^ (((rr0 + 0) & 7) << 3)] = f2bf(fast_tanh(acc[0][0] + pj00));
      s0w[((rr0 + 1) * U + col0) ^ (((rr0 + 1) & 7) << 3)] = f2bf(fast_tanh(acc[0][1] + pj01));
      s0w[((rr0 + 2) * U + col0) ^ (((rr0 + 2) & 7) << 3)] = f2bf(fast_tanh(acc[0][2] + pj02));
      s0w[((rr0 + 3) * U + col0) ^ (((rr0 + 3) & 7) << 3)] = f2bf(fast_tanh(acc[0][3] + pj03));
      s0w[((rr0 + 0) * U + col1) ^ (((rr0 + 0) & 7) << 3)] = f2bf(fast_tanh(acc[1][0] + pj10));
      s0w[((rr0 + 1) * U + col1) ^ (((rr0 + 1) & 7) << 3)] = f2bf(fast_tanh(acc[1][1] + pj11));
      s0w[((rr0 + 2) * U + col1) ^ (((rr0 + 2) & 7) << 3)] = f2bf(fast_tanh(acc[1][2] + pj12));
      s0w[((rr0 + 3) * U + col1) ^ (((rr0 + 3) & 7) << 3)] = f2bf(fast_tanh(acc[1][3] + pj13));
    }
    __syncthreads();   // B_a: o0 visible

    // ---------- layer 1: o1 = tanh(o0 @ Wx1 + s1 @ Wh1 + b1) ----------
    acc[0] = 0.0f; acc[1] = 0.0f;
    run_segment<32>(w1p, lofs, s0w, s1r, aBase, aSwz, acc);
#pragma unroll
    for (int j = 0; j < 4; ++j){
      const int rr = rr0 + j;
      s1w[(rr * U + col0) ^ ((rr & 7) << 3)] = f2bf(fast_tanh(acc[0][j] + b1v0));
      s1w[(rr * U + col1) ^ ((rr & 7) << 3)] = f2bf(fast_tanh(acc[1][j] + b1v1));
    }
    __syncthreads();   // B_b: o1 visible

    // ---------- layer 2: o2 = tanh(o1 @ Wx2 + s2 @ Wh2 + b2) ----------
    acc[0] = 0.0f; acc[1] = 0.0f;
    run_segment<32>(w2p, lofs, s1w, s2r, aBase, aSwz, acc);
#pragma unroll
    for (int j = 0; j < 4; ++j){
      const int rr = rr0 + j;
      s2w[(rr * U + col0) ^ ((rr & 7) << 3)] = f2bf(fast_tanh(acc[0][j] + b2v0));
      s2w[(rr * U + col1) ^ ((rr & 7) << 3)] = f2bf(fast_tanh(acc[1][j] + b2v1));
    }
    // no barrier: next step's B_a/B_b cover all cross-step dependencies
  }
  __syncthreads();     // final o2 (in buffer (79&1)^1 = 0) visible

  // ---------- output: sigmoid(s2 @ Wout + bout), one wave per row ----------
  {
    const unsigned short* sf = smem + 4 * 8192;   // st2 buffer 0
    const int r = wid;
    float v = 0.0f;
#pragma unroll
    for (int jj = 0; jj < 8; ++jj){
      const int n = lane + jj * 64;
      v += bf2f(sf[(r * U + n) ^ ((r & 7) << 3)]) * Wout[n];
    }
#pragma unroll
    for (int off = 32; off > 0; off >>= 1)
      v += __shfl_down(v, off, 64);
    if (lane == 0)
      out[rowbase + r] = 1.0f / (1.0f + __expf(-(v + bout[0])));
  }
}

extern "C" void kernel_launch(void* const* d_in, const int* in_sizes, int n_in,
                              void* d_out, int out_size, void* d_ws, size_t ws_size,
                              hipStream_t stream){
  (void)in_sizes; (void)n_in; (void)out_size; (void)ws_size;
  const int*   tokens = (const int*)  d_in[0];
  const float* emb  = (const float*)d_in[1];
  const float* Wx0  = (const float*)d_in[2];
  const float* Wh0  = (const float*)d_in[3];
  const float* b0   = (const float*)d_in[4];
  const float* Wx1  = (const float*)d_in[5];
  const float* Wh1  = (const float*)d_in[6];
  const float* b1   = (const float*)d_in[7];
  const float* Wx2  = (const float*)d_in[8];
  const float* Wh2  = (const float*)d_in[9];
  const float* b2   = (const float*)d_in[10];
  const float* Wout = (const float*)d_in[11];
  const float* bout = (const float*)d_in[12];

  char* ws = (char*)d_ws;
  float* proj = (float*)ws;                                   // 20.48 MB
  unsigned short* P0 = (unsigned short*)(ws + (size_t)TW * U * 4);  // 512 KB packed bf16
  unsigned short* P1 = P0 + (size_t)16 * 16 * 1024;                 // 1 MB
  unsigned short* P2 = P1 + (size_t)16 * 32 * 1024;                 // 1 MB

  proj_kernel<<<TW / 16, 256, 0, stream>>>(emb, Wx0, b0, proj);
  const int pblk = (U * U + 255) / 256;   // 512*512 elems per source matrix
  pack_frag<<<pblk, 256, 0, stream>>>(Wh0, P0, U, 0, 16);
  pack_frag<<<pblk, 256, 0, stream>>>(Wx1, P1, U, 0, 32);
  pack_frag<<<pblk, 256, 0, stream>>>(Wh1, P1, U, U, 32);
  pack_frag<<<pblk, 256, 0, stream>>>(Wx2, P2, U, 0, 32);
  pack_frag<<<pblk, 256, 0, stream>>>(Wh2, P2, U, U, 32);

  static const int kLds = 98304;   // 6 x 16 KiB double-buffered states
  (void)hipFuncSetAttribute((const void*)rnn_persist,
                            hipFuncAttributeMaxDynamicSharedMemorySize, kLds);
  rnn_persist<<<NBLK, NTHR, kLds, stream>>>(tokens, proj, P0, P1, P2,
                                            b1, b2, Wout, bout, (float*)d_out);
}